// Round 1
// baseline (23.989 us; speedup 1.0000x reference)
//
#include <hip/hip_runtime.h>
#include <math.h>

// out[bn, y, x] = (valid && y in [sy1,sy2) && x in [sx1,sx2) ? feat[rowS(y)] : 0)
//              + (valid && y in [oy1,oy2) && x in [ox1,ox2) ? feat[rowO(y)] : 0)
// rowS(y) = clip((y - sy1) * C / sh, 0, C-1), nearest-neighbor 1-D interp.
__global__ void rs_rel_spatial_kernel(const float* __restrict__ rel,
                                      const int* __restrict__ bbox,
                                      float* __restrict__ out,
                                      int C, int w) {
    const int bn = blockIdx.x;
    extern __shared__ float smem[];
    float* sval = smem;      // [w] subject-box per-row value (0 if masked)
    float* oval = smem + w;  // [w] object-box per-row value

    const int* bb = bbox + (size_t)bn * 8;
    const int sx1 = bb[0] >> 1, sy1 = bb[1] >> 1, sx2 = bb[2] >> 1, sy2 = bb[3] >> 1;
    const int ox1 = bb[4] >> 1, oy1 = bb[5] >> 1, ox2 = bb[6] >> 1, oy2 = bb[7] >> 1;
    const int sh = sy2 - sy1, sw_ = sx2 - sx1;
    const int oh = oy2 - oy1, ow_ = ox2 - ox1;
    const bool valid = (sh >= 5) & (sw_ >= 5) & (oh >= 5) & (ow_ >= 5);

    const float* feat = rel + (size_t)bn * C;

    // Phase 1: per-row gathered values into LDS (one int-div per row, not per elem)
    for (int r = threadIdx.x; r < 2 * w; r += blockDim.x) {
        float v = 0.f;
        if (r < w) {
            const int y = r;
            if (valid && y >= sy1 && y < sy2) {
                int row = (y - sy1) * C / sh;       // sh >= 5 when valid
                if (row > C - 1) row = C - 1;
                v = feat[row];
            }
            sval[y] = v;
        } else {
            const int y = r - w;
            if (valid && y >= oy1 && y < oy2) {
                int row = (y - oy1) * C / oh;
                if (row > C - 1) row = C - 1;
                v = feat[row];
            }
            oval[y] = v;
        }
    }
    __syncthreads();

    float* obase = out + (size_t)bn * w * w;

    if ((w & 3) == 0) {
        // Vectorized: each thread writes one float4 (4 consecutive x)
        const int qpr = w >> 2;            // float4 quads per row
        const int total = w * qpr;
        for (int q = threadIdx.x; q < total; q += blockDim.x) {
            const int y  = q / qpr;
            const int x0 = (q - y * qpr) << 2;
            const float sv = sval[y];
            const float ov = oval[y];
            float4 res;
            float* rp = &res.x;
#pragma unroll
            for (int j = 0; j < 4; ++j) {
                const int x = x0 + j;
                float acc = 0.f;
                if (x >= sx1 && x < sx2) acc += sv;
                if (x >= ox1 && x < ox2) acc += ov;
                rp[j] = acc;
            }
            *reinterpret_cast<float4*>(obase + (size_t)y * w + x0) = res;
        }
    } else {
        // Scalar fallback for odd w
        const int total = w * w;
        for (int i = threadIdx.x; i < total; i += blockDim.x) {
            const int y = i / w;
            const int x = i - y * w;
            float acc = 0.f;
            if (x >= sx1 && x < sx2) acc += sval[y];
            if (x >= ox1 && x < ox2) acc += oval[y];
            obase[i] = acc;
        }
    }
}

extern "C" void kernel_launch(void* const* d_in, const int* in_sizes, int n_in,
                              void* d_out, int out_size, void* d_ws, size_t ws_size,
                              hipStream_t stream) {
    const float* rel  = (const float*)d_in[0];
    const int*   bbox = (const int*)d_in[1];
    float*       out  = (float*)d_out;

    // Shapes from flat sizes: bbox is [B,N,8] -> BN; rel is [BN,C]; out is [BN,w,w]
    const int BN = in_sizes[1] / 8;
    const int C  = in_sizes[0] / BN;
    const int w  = (int)(sqrt((double)(out_size / BN)) + 0.5);

    dim3 grid(BN);
    dim3 block(256);
    const size_t shmem = (size_t)2 * w * sizeof(float);
    hipLaunchKernelGGL(rs_rel_spatial_kernel, grid, block, shmem, stream,
                       rel, bbox, out, C, w);
}